// Round 3
// baseline (31.699 us; speedup 1.0000x reference)
//
#include <hip/hip_runtime.h>

typedef __attribute__((ext_vector_type(4))) float f32x4;
typedef __attribute__((ext_vector_type(8))) short bf16x8;

// x: [B, 64, 128] fp32 ; out: [B, 2016] fp32
constexpr int F = 64;
constexpr int D = 128;
constexpr int NPAIR = 2016;   // 64*63/2
constexpr int NB = 4;         // batches per block (register-prefetch pipeline)

// fp32 -> bf16 round-to-nearest-even
__device__ inline unsigned f2bf(float f) {
  unsigned u = __float_as_uint(f);
  return (u + 0x7FFFu + ((u >> 16) & 1u)) >> 16;
}

// Raw barrier: wave's own LDS ops drained (lgkmcnt), but global prefetch
// loads (vmcnt) stay in flight across the barrier — unlike __syncthreads,
// which emits s_waitcnt vmcnt(0) and would kill the pipeline.
#define BAR() do { asm volatile("s_waitcnt lgkmcnt(0)" ::: "memory"); \
                   __builtin_amdgcn_s_barrier(); \
                   asm volatile("" ::: "memory"); } while (0)

__global__ __launch_bounds__(256, 4)
void gram_upper_kernel(const float* __restrict__ x, float* __restrict__ out,
                       int Btot) {
  // 64 rows x 256 B (bf16), 16B-granule XOR swizzle: granule' = g ^ (row&15)
  // -> conflict-free ds_write_b64 staging AND conflict-free ds_read_b128 frags.
  __shared__ __align__(16) unsigned char lds[F * 256];

  const int t  = threadIdx.x;
  const int w  = t >> 6;     // wave id
  const int l  = t & 63;
  const int lr = l & 15;     // row-within-tile (A) / col-within-tile (B,D)
  const int lk = l >> 4;     // k-group 0..3

  const long b0 = (long)blockIdx.x * NB;

  f32x4 ra[8], rb[8];        // two register staging buffers (32 VGPR each)

  auto loadb = [&](f32x4 (&r)[8], long batch) {
    const f32x4* p = reinterpret_cast<const f32x4*>(x + batch * (F * D));
#pragma unroll
    for (int k = 0; k < 8; ++k) r[k] = p[t + 256 * k];
  };

  auto stage = [&](const f32x4 (&r)[8]) {
#pragma unroll
    for (int k = 0; k < 8; ++k) {
      int idx4 = t + 256 * k;              // float4 index in batch
      int e    = idx4 << 2;                // element index
      int f    = e >> 7;                   // row 0..63
      int d0   = e & 127;                  // col (multiple of 4)
      int off  = f * 256 + (((d0 >> 3) ^ (f & 15)) << 4) + ((d0 & 4) << 1);
      uint2 pk;
      pk.x = f2bf(r[k].x) | (f2bf(r[k].y) << 16);
      pk.y = f2bf(r[k].z) | (f2bf(r[k].w) << 16);
      *reinterpret_cast<uint2*>(lds + off) = pk;
    }
  };

  // 10 upper-triangular 16x16 tiles, balanced 3/3/2/2 across 4 waves.
  // desc byte s = (ti<<4)|tj ; byte 3 = tile count.
  auto compute = [&](long batch) {
    float* ob = out + batch * NPAIR;
    unsigned desc = (w == 0) ? 0x03020100u : (w == 1) ? 0x03121103u
                  : (w == 2) ? 0x02002213u : 0x02003323u;
    int cnt = desc >> 24;
#pragma unroll
    for (int s = 0; s < 3; ++s) {
      if (s < cnt) {
        int ti = (desc >> (8 * s + 4)) & 15;
        int tj = (desc >> (8 * s)) & 15;
        f32x4 acc = {0.f, 0.f, 0.f, 0.f};
#pragma unroll
        for (int kk = 0; kk < 4; ++kk) {
          int gsw = ((kk << 2) + lk) ^ lr;   // rows differ by mult of 16 -> same swizzle
          bf16x8 a  = *reinterpret_cast<const bf16x8*>(lds + (ti * 16 + lr) * 256 + gsw * 16);
          bf16x8 bv = *reinterpret_cast<const bf16x8*>(lds + (tj * 16 + lr) * 256 + gsw * 16);
          acc = __builtin_amdgcn_mfma_f32_16x16x32_bf16(a, bv, acc, 0, 0, 0);
        }
        // C/D map: col = lane&15, row = (lane>>4)*4 + reg
        int j  = tj * 16 + lr;
        int ib = ti * 16 + lk * 4;
#pragma unroll
        for (int r = 0; r < 4; ++r) {
          int i = ib + r;
          if (j > i) {
            int p = i * 63 - ((i * (i - 1)) >> 1) + (j - i - 1);
            ob[p] = acc[r];
          }
        }
      }
    }
  };

  const bool v1 = (b0 + 1 < Btot), v2 = (b0 + 2 < Btot), v3 = (b0 + 3 < Btot);

  // ---- pipeline: prefetch batch n+1 into regs while computing batch n ----
  loadb(ra, b0);
  stage(ra);
  if (v1) loadb(rb, b0 + 1);   // in flight across BAR + compute
  BAR();
  compute(b0);
  BAR();
  if (v1) {
    stage(rb);
    if (v2) loadb(ra, b0 + 2);
    BAR();
    compute(b0 + 1);
    BAR();
  }
  if (v2) {
    stage(ra);
    if (v3) loadb(rb, b0 + 3);
    BAR();
    compute(b0 + 2);
    BAR();
  }
  if (v3) {
    stage(rb);
    BAR();
    compute(b0 + 3);
  }
}

extern "C" void kernel_launch(void* const* d_in, const int* in_sizes, int n_in,
                              void* d_out, int out_size, void* d_ws, size_t ws_size,
                              hipStream_t stream) {
  const float* x = (const float*)d_in[0];
  float* out = (float*)d_out;
  const int B = in_sizes[0] / (F * D);          // 4096
  const int grid = (B + NB - 1) / NB;           // 1024
  gram_upper_kernel<<<dim3(grid), dim3(256), 0, stream>>>(x, out, B);
}

// Round 4
// 30.198 us; speedup vs baseline: 1.0497x; 1.0497x over previous
//
#include <hip/hip_runtime.h>

typedef __attribute__((ext_vector_type(4))) float f32x4;
typedef __attribute__((ext_vector_type(8))) short bf16x8;

// x: [B, 64, 128] fp32 ; out: [B, 2016] fp32
constexpr int F = 64;
constexpr int D = 128;
constexpr int NPAIR = 2016;   // 64*63/2

// fp32 -> bf16 round-to-nearest-even
__device__ inline unsigned f2bf(float f) {
  unsigned u = __float_as_uint(f);
  return (u + 0x7FFFu + ((u >> 16) & 1u)) >> 16;
}

// One block per batch: 256 threads = 4 waves.
// Only the 10 upper-triangular 16x16 tiles are computed (gram is symmetric),
// balanced 3/3/2/2 across the 4 waves (12/12/8/8 MFMA).
__global__ __launch_bounds__(256)
void gram_upper_kernel(const float* __restrict__ x, float* __restrict__ out) {
  // 64 rows x 256 B (bf16), 16B-granule XOR swizzle: granule' = g ^ (row&15)
  // -> conflict-free ds_write_b64 staging AND conflict-free ds_read_b128 frags.
  __shared__ __align__(16) unsigned char lds[F * 256];

  const int b = blockIdx.x;
  const int t = threadIdx.x;
  const float* xb = x + (size_t)b * (F * D);

  // ---- Stage: global fp32 (coalesced float4) -> bf16 -> swizzled LDS ----
  // Per-iteration load+convert+store keeps VGPR low (full occupancy);
  // the compiler pipelines the 8 iterations' loads itself.
#pragma unroll
  for (int k = 0; k < 8; ++k) {
    int idx4 = t + 256 * k;                         // float4 index, [0, 2048)
    f32x4 v = reinterpret_cast<const f32x4*>(xb)[idx4];
    int e  = idx4 << 2;                             // element index
    int f  = e >> 7;                                // row 0..63
    int d0 = e & 127;                               // col (multiple of 4)
    int off = f * 256 + (((d0 >> 3) ^ (f & 15)) << 4) + ((d0 & 4) << 1);
    uint2 pk;
    pk.x = f2bf(v.x) | (f2bf(v.y) << 16);
    pk.y = f2bf(v.z) | (f2bf(v.w) << 16);
    *reinterpret_cast<uint2*>(lds + off) = pk;
  }
  __syncthreads();

  const int w  = t >> 6;     // wave id
  const int l  = t & 63;
  const int lr = l & 15;     // row-within-tile (A) / col-within-tile (B,D)
  const int lk = l >> 4;     // k-group 0..3

  // Tile schedule: desc byte s = (ti<<4)|tj ; byte 3 = tile count.
  // w0: (0,0)(0,1)(0,2)  w1: (0,3)(1,1)(1,2)  w2: (1,3)(2,2)  w3: (2,3)(3,3)
  const unsigned desc = (w == 0) ? 0x03020100u : (w == 1) ? 0x03121103u
                      : (w == 2) ? 0x02002213u : 0x02003323u;
  const int cnt = desc >> 24;

  float* ob = out + (size_t)b * NPAIR;

#pragma unroll
  for (int s = 0; s < 3; ++s) {
    if (s < cnt) {
      int ti = (desc >> (8 * s + 4)) & 15;
      int tj = (desc >> (8 * s)) & 15;
      f32x4 acc = {0.f, 0.f, 0.f, 0.f};
#pragma unroll
      for (int kk = 0; kk < 4; ++kk) {
        int gsw = ((kk << 2) + lk) ^ lr;   // rows differ by mult of 16 -> same swizzle
        bf16x8 a  = *reinterpret_cast<const bf16x8*>(lds + (ti * 16 + lr) * 256 + gsw * 16);
        bf16x8 bv = *reinterpret_cast<const bf16x8*>(lds + (tj * 16 + lr) * 256 + gsw * 16);
        acc = __builtin_amdgcn_mfma_f32_16x16x32_bf16(a, bv, acc, 0, 0, 0);
      }
      // C/D map: col = lane&15, row = (lane>>4)*4 + reg
      int j  = tj * 16 + lr;
      int ib = ti * 16 + lk * 4;
      if (ti != tj) {
        // off-diagonal tile: every (i,j) has j > i — no predication
#pragma unroll
        for (int r = 0; r < 4; ++r) {
          int i = ib + r;
          int p = i * 63 - ((i * (i - 1)) >> 1) + (j - i - 1);
          ob[p] = acc[r];
        }
      } else {
#pragma unroll
        for (int r = 0; r < 4; ++r) {
          int i = ib + r;
          if (j > i) {
            int p = i * 63 - ((i * (i - 1)) >> 1) + (j - i - 1);
            ob[p] = acc[r];
          }
        }
      }
    }
  }
}

extern "C" void kernel_launch(void* const* d_in, const int* in_sizes, int n_in,
                              void* d_out, int out_size, void* d_ws, size_t ws_size,
                              hipStream_t stream) {
  const float* x = (const float*)d_in[0];
  float* out = (float*)d_out;
  const int B = in_sizes[0] / (F * D);   // 4096
  gram_upper_kernel<<<dim3(B), dim3(256), 0, stream>>>(x, out);
}